// Round 5
// baseline (71.783 us; speedup 1.0000x reference)
//
#include <hip/hip_runtime.h>
#include <hip/hip_cooperative_groups.h>
#include <math.h>

namespace cg = cooperative_groups;

#define N_    2
#define C_    256
#define H_    16
#define W_    16
#define T_    8
#define P_    256      // H_*W_
#define PAD_  3
#define CPC_  4                    // channels per chunk
#define CHUNKS_ (C_ / CPC_)        // 64
#define NB_   (N_ * CHUNKS_)       // 128 blocks
#define ROWS_ 24                   // padded plane 24x24, 16B-aligned interior
#define PLSZ_ (ROWS_ * ROWS_)      // 576 floats / channel

// ws layout (floats): base_part[NB_ * P_], (n*CHUNKS_+chunk)*P_ + pix

__global__ __launch_bounds__(256)
void fused_kernel(const float* __restrict__ feat,
                  const float* __restrict__ wt,
                  const float* __restrict__ bias,
                  const int* __restrict__ tgt,
                  float* __restrict__ ws,
                  float* __restrict__ out) {
    int b = blockIdx.x;
    int tid = threadIdx.x;

    __shared__ float pl[CPC_ * PLSZ_];   // phase A: padded planes
    __shared__ float wsm[CPC_ * 49];
    __shared__ float s_tgt[T_][P_];      // phase B
    __shared__ float s_ktab[49];
    __shared__ float s_area[T_];
    __shared__ float s_st[P_];
    __shared__ int   s_cnt[16];
    __shared__ int   s_idx[16];
    __shared__ float s_red[4];

    // ---------- phase A: conv partials over CPC_ channels ----------
    {
        int n = b / CHUNKS_;
        int chunk = b % CHUNKS_;
        int c0 = chunk * CPC_;

        float4* z4 = (float4*)pl;        // zero planes (halo must be 0)
        #pragma unroll
        for (int i = tid; i < CPC_ * PLSZ_ / 4; i += 256)
            z4[i] = make_float4(0.f, 0.f, 0.f, 0.f);
        if (tid < CPC_ * 49) wsm[tid] = wt[c0 * 49 + tid];
        __syncthreads();

        // stage 4 contiguous channel planes: 256 float4 = 1/thread, aligned dest
        const float4* src4 = (const float4*)(feat + (size_t)(n * C_ + c0) * P_);
        int c = tid >> 6, r = tid & 63, hh = r >> 2, w4 = r & 3;
        *(float4*)(pl + c * PLSZ_ + (hh + 3) * ROWS_ + 4 + w4 * 4) = src4[tid];
        __syncthreads();

        int h = tid >> 4, w = tid & 15;
        float acc[CPC_];
        #pragma unroll
        for (int c2 = 0; c2 < CPC_; ++c2) acc[c2] = 0.f;
        #pragma unroll
        for (int c2 = 0; c2 < CPC_; ++c2) {
            const float* p  = pl + c2 * PLSZ_ + h * ROWS_ + (w + 1);
            const float* wc = wsm + c2 * 49;
            #pragma unroll
            for (int kh = 0; kh < 7; ++kh)
                #pragma unroll
                for (int kw = 0; kw < 7; ++kw)
                    acc[c2] += p[kh * ROWS_ + kw] * wc[kh * 7 + kw];
        }
        ws[(size_t)b * P_ + tid] = (acc[0] + acc[1]) + (acc[2] + acc[3]);

        if (b == 0 && tid == 0)
            __hip_atomic_store(out, 0.f, __ATOMIC_RELAXED, __HIP_MEMORY_SCOPE_AGENT);
    }

    __threadfence();                     // release ws across XCDs
    cg::this_grid().sync();
    __threadfence();                     // acquire

    // ---------- phase B: loss, blocks 0..31 ----------
    if (b >= N_ * 16) return;
    int n = b >> 4, pg = b & 15;

    for (int i = tid; i < T_ * P_; i += 256)
        s_tgt[0][i] = (float)tgt[n * T_ * P_ + i];
    if (tid < 49) s_ktab[tid] = wt[C_ * 49 + tid];
    __syncthreads();

    int wave = tid >> 6, lane = tid & 63;
    #pragma unroll
    for (int k = 0; k < 2; ++k) {        // areas: wave handles t = 2*wave+k
        int t = wave * 2 + k;
        float v = s_tgt[t][lane] + s_tgt[t][lane + 64]
                + s_tgt[t][lane + 128] + s_tgt[t][lane + 192];
        #pragma unroll
        for (int off = 32; off; off >>= 1) v += __shfl_down(v, off, 64);
        if (lane == 0) s_area[t] = v;
    }
    {
        float s = 0.f;                   // s_st[pix] = sum_t tgt[t][pix]
        #pragma unroll
        for (int t = 0; t < T_; ++t) s += s_tgt[t][tid];
        s_st[tid] = s;
    }
    __syncthreads();

    if (tid < 16) {                      // per-p cnt + first-argmin
        int p = pg * 16 + tid;
        int cnt = 0; float best = 3.402823466e38f; int idx = 0;
        #pragma unroll
        for (int t = 0; t < T_; ++t) {
            float on = s_tgt[t][p];
            cnt += (int)on;
            if (on > 0.f && s_area[t] < best) { best = s_area[t]; idx = t; }
        }
        s_cnt[tid] = cnt; s_idx[tid] = idx;
    }

    // base[pix]: sum 64 partials; agent-scope loads dodge stale L2 lines
    float base = 0.f;
    const float* wsb = ws + (size_t)n * CHUNKS_ * P_ + tid;
    #pragma unroll
    for (int j = 0; j < CHUNKS_; ++j)
        base += __hip_atomic_load(&wsb[j * P_], __ATOMIC_RELAXED,
                                  __HIP_MEMORY_SCOPE_AGENT);
    __syncthreads();

    float bv = bias[0];
    float st = s_st[tid];
    int h = tid >> 4, wcol = tid & 15;
    float lsum = 0.f;
    #pragma unroll
    for (int it = 0; it < 16; ++it) {
        int p = pg * 16 + it;            // block-uniform
        int ph = p >> 4, pw = p & 15;
        int dh = ph - h + PAD_, dw = pw - wcol + PAD_;
        float kc = ((unsigned)dh < 7u && (unsigned)dw < 7u) ? s_ktab[dh * 7 + dw] : 0.f;
        float m = 1.f / (1.f + expf(-(base + kc + bv)));
        float contrib = (s_cnt[it] > 0) ? fabsf(m - s_tgt[s_idx[it]][tid]) : st * m;
        lsum += contrib;
    }

    #pragma unroll
    for (int off = 32; off; off >>= 1) lsum += __shfl_down(lsum, off, 64);
    if (lane == 0) s_red[wave] = lsum;
    __syncthreads();
    if (tid == 0)
        atomicAdd(out, (s_red[0] + s_red[1] + s_red[2] + s_red[3]) * (1.0f / 256.0f));
}

extern "C" void kernel_launch(void* const* d_in, const int* in_sizes, int n_in,
                              void* d_out, int out_size, void* d_ws, size_t ws_size,
                              hipStream_t stream) {
    const float* feat = (const float*)d_in[0];
    const float* wt   = (const float*)d_in[1];
    const float* bias = (const float*)d_in[2];
    const int*   tgt  = (const int*)d_in[3];
    float* out = (float*)d_out;
    float* ws  = (float*)d_ws;

    void* args[] = { &feat, &wt, &bias, &tgt, &ws, &out };
    hipLaunchCooperativeKernel((const void*)fused_kernel,
                               dim3(NB_), dim3(256), args, 0, stream);
}

// Round 6
// 17.054 us; speedup vs baseline: 4.2092x; 4.2092x over previous
//
#include <hip/hip_runtime.h>
#include <math.h>

#define N_   2
#define C_   256
#define H_   16
#define W_   16
#define T_   8
#define P_   256     // H_*W_
#define PW_  12      // padded plane width (mult of 4; c-stride 84 -> 2-way banks = free)
#define PH_  7       // plane rows (kh 0..6)
#define PSZ_ (PH_ * PW_)   // 84 floats per channel

// Block = (n, row h, quarter qx): owns 4 pixels (cols qx*4..qx*4+3) of row h.
// 1024 threads = 256 channels x 4 pixels. Computes base for its pixels over all
// channels locally -> no inter-block dependency -> single regular kernel.

__global__ __launch_bounds__(1024)
void fused(const float* __restrict__ feat,
           const float* __restrict__ wt,
           const float* __restrict__ bias,
           const int* __restrict__ tgt,
           float* __restrict__ out) {
    int b = blockIdx.x;                 // n*64 + h*4 + qx
    int tid = threadIdx.x;
    int n = b >> 6, h = (b >> 2) & 15, qx = b & 3;

    __shared__ float pl[C_ * PSZ_];     // 84 KB padded feat slabs
    __shared__ float wsm[C_ * 49];      // 49 KB channel weights
    __shared__ float s_tgt[T_][P_];     // 8 KB targets (as float)
    __shared__ float s_ktab[49];        // onehot-channel weights
    __shared__ float s_area[T_];
    __shared__ float s_st[4];           // sum_t tgt[t][gpix] for the 4 owned pixels
    __shared__ int   s_cnt[P_];
    __shared__ int   s_idx[P_];
    __shared__ float s_base[4];
    __shared__ float s_red[64];

    // ---------- P0: stage everything ----------
    // planes: for channel c, plane row kh (global row y=h-3+kh), 3 float4 per row.
    // LDS col L maps global col gc = qx*4-4+L; window reads L = px+kw+1 in [1,10].
    // Out-of-image float4s write zero -> halo zeroing is free.
    {
        const float4* f4 = (const float4*)(feat + (size_t)n * C_ * P_);
        #pragma unroll
        for (int k = 0; k < 6; ++k) {
            int i = tid + k * 1024;                 // float4 index, < 256*21
            if (i < C_ * 21) {
                int c  = i / 21, r = i - c * 21;
                int kh = r / 3,  k4 = r - kh * 3;
                int y   = h - 3 + kh;
                int gc0 = qx * 4 - 4 + k4 * 4;      // in {-4,0,...,20}, mult of 4
                float4 v = make_float4(0.f, 0.f, 0.f, 0.f);
                if ((unsigned)y < 16u && (unsigned)gc0 < 16u)
                    v = f4[c * 64 + y * 4 + (gc0 >> 2)];
                *(float4*)(pl + c * PSZ_ + kh * PW_ + k4 * 4) = v;
            }
        }
        const float4* w4 = (const float4*)wt;       // 256*49 = 3136 float4, exact
        #pragma unroll
        for (int k = 0; k < 4; ++k) {
            int i = tid + k * 1024;
            if (i < C_ * 49 / 4) ((float4*)wsm)[i] = w4[i];
        }
        for (int i = tid; i < T_ * P_; i += 1024)
            s_tgt[0][i] = (float)tgt[n * T_ * P_ + i];
        if (tid < 49) s_ktab[tid] = wt[C_ * 49 + tid];
    }
    __syncthreads();

    int wid = tid >> 6, lane = tid & 63;

    // ---------- P1: target tables (waves 0..8) — no barrier needed before conv
    if (wid < T_) {
        int t = wid;
        float v = s_tgt[t][lane] + s_tgt[t][lane + 64]
                + s_tgt[t][lane + 128] + s_tgt[t][lane + 192];
        #pragma unroll
        for (int off = 32; off; off >>= 1) v += __shfl_down(v, off, 64);
        if (lane == 0) s_area[t] = v;
    } else if (wid == 8 && lane < 4) {
        int gpix = h * 16 + qx * 4 + lane;
        float s = 0.f;
        #pragma unroll
        for (int t = 0; t < T_; ++t) s += s_tgt[t][gpix];
        s_st[lane] = s;
    }

    // ---------- P2: conv — thread = (channel c, pixel px)
    int c  = tid >> 2;
    int px = tid & 3;
    float acc = 0.f;
    {
        const float* pp = pl + c * PSZ_ + (px + 1);
        const float* wc = wsm + c * 49;
        #pragma unroll
        for (int kh = 0; kh < 7; ++kh)
            #pragma unroll
            for (int kw = 0; kw < 7; ++kw)
                acc += pp[kh * PW_ + kw] * wc[kh * 7 + kw];
    }
    // reduce over the 16 channels within each wave (pix lanes are stride-4-aligned)
    #pragma unroll
    for (int off = 4; off < 64; off <<= 1) acc += __shfl_down(acc, off, 64);
    if (lane < 4) s_red[wid * 4 + lane] = acc;
    __syncthreads();

    // ---------- P3: finish base; cnt/idx per p (parallel, disjoint threads)
    if (tid < 4) {
        float s = 0.f;
        #pragma unroll
        for (int wv = 0; wv < 16; ++wv) s += s_red[wv * 4 + tid];
        s_base[tid] = s;
    } else if (tid >= 64 && tid < 64 + P_) {
        int p = tid - 64;
        int cnt = 0; float best = 3.402823466e38f; int idx = 0;
        #pragma unroll
        for (int t = 0; t < T_; ++t) {
            float on = s_tgt[t][p];
            cnt += (int)on;
            if (on > 0.f && s_area[t] < best) { best = s_area[t]; idx = t; }
        }
        s_cnt[p] = cnt; s_idx[p] = idx;
    }
    __syncthreads();

    // ---------- P4: loss — thread = (p, px)
    float bv = bias[0];
    int p = tid >> 2;
    int gpix = h * 16 + qx * 4 + px;
    int ph = p >> 4, pw = p & 15;
    int dh = ph - h + 3, dw = pw - (qx * 4 + px) + 3;
    float kc = ((unsigned)dh < 7u && (unsigned)dw < 7u) ? s_ktab[dh * 7 + dw] : 0.f;
    float m = 1.f / (1.f + expf(-(s_base[px] + kc + bv)));
    float contrib = (s_cnt[p] > 0) ? fabsf(m - s_tgt[s_idx[p]][gpix])
                                   : s_st[px] * m;

    #pragma unroll
    for (int off = 32; off; off >>= 1) contrib += __shfl_down(contrib, off, 64);
    if (lane == 0) s_red[wid] = contrib;        // reuse s_red (conv partials consumed)
    __syncthreads();
    if (tid == 0) {
        float s = 0.f;
        #pragma unroll
        for (int i = 0; i < 16; ++i) s += s_red[i];
        atomicAdd(out, s * (1.0f / 256.0f));
    }
}

extern "C" void kernel_launch(void* const* d_in, const int* in_sizes, int n_in,
                              void* d_out, int out_size, void* d_ws, size_t ws_size,
                              hipStream_t stream) {
    const float* feat = (const float*)d_in[0];
    const float* wt   = (const float*)d_in[1];
    const float* bias = (const float*)d_in[2];
    const int*   tgt  = (const int*)d_in[3];
    float* out = (float*)d_out;

    hipMemsetAsync(out, 0, sizeof(float), stream);   // graph-legal async memset node
    fused<<<N_ * H_ * 4, 1024, 0, stream>>>(feat, wt, bias, tgt, out);
}

// Round 7
// 13.745 us; speedup vs baseline: 5.2226x; 1.2408x over previous
//
#include <hip/hip_runtime.h>
#include <math.h>

#define N_   2
#define C_   256
#define H_   16
#define W_   16
#define T_   8
#define P_   256     // H_*W_
#define PW_  12      // padded plane width (c-stride 84 -> balanced banks)
#define PH_  7       // plane rows (kh 0..6)
#define PSZ_ (PH_ * PW_)   // 84 floats per channel
#define MAGIC_ 0x5BD1E995u

// Block = (n, row h, quarter qx): owns 4 pixels. 1024 threads = 256 ch x 4 px.
// Single kernel node: block partials go to ws slots {partial, flag} (64B apart);
// block 0 spin-combines (agent-scope acquire), writes out, resets flags to 0.

__global__ __launch_bounds__(1024)
void fused(const float* __restrict__ feat,
           const float* __restrict__ wt,
           const float* __restrict__ bias,
           const int* __restrict__ tgt,
           float* __restrict__ ws,
           float* __restrict__ out) {
    int b = blockIdx.x;                 // n*64 + h*4 + qx
    int tid = threadIdx.x;
    int n = b >> 6, h = (b >> 2) & 15, qx = b & 3;

    __shared__ float pl[C_ * PSZ_];     // 84 KB padded feat slabs
    __shared__ float wsm[C_ * 49];      // 49 KB channel weights
    __shared__ float s_tgt[T_][P_];     // 8 KB targets (as float)
    __shared__ float s_ktab[49];
    __shared__ float s_area[T_];
    __shared__ float s_st[4];
    __shared__ int   s_cnt[P_];
    __shared__ int   s_idx[P_];
    __shared__ float s_base[4];
    __shared__ float s_red[64];
    __shared__ float s_part[128];

    // ---------- P0: stage everything ----------
    {
        const float4* f4 = (const float4*)(feat + (size_t)n * C_ * P_);
        #pragma unroll
        for (int k = 0; k < 6; ++k) {
            int i = tid + k * 1024;                 // float4 index, < 256*21
            if (i < C_ * 21) {
                int c  = i / 21, r = i - c * 21;
                int kh = r / 3,  k4 = r - kh * 3;
                int y   = h - 3 + kh;
                int gc0 = qx * 4 - 4 + k4 * 4;
                float4 v = make_float4(0.f, 0.f, 0.f, 0.f);
                if ((unsigned)y < 16u && (unsigned)gc0 < 16u)
                    v = f4[c * 64 + y * 4 + (gc0 >> 2)];
                *(float4*)(pl + c * PSZ_ + kh * PW_ + k4 * 4) = v;
            }
        }
        const float4* w4 = (const float4*)wt;       // 256*49/4 = 3136 float4
        #pragma unroll
        for (int k = 0; k < 4; ++k) {
            int i = tid + k * 1024;
            if (i < C_ * 49 / 4) ((float4*)wsm)[i] = w4[i];
        }
        for (int i = tid; i < T_ * P_; i += 1024)
            s_tgt[0][i] = (float)tgt[n * T_ * P_ + i];
        if (tid < 49) s_ktab[tid] = wt[C_ * 49 + tid];
    }
    __syncthreads();

    int wid = tid >> 6, lane = tid & 63;

    // ---------- P1: target tables (waves 0..8)
    if (wid < T_) {
        int t = wid;
        float v = s_tgt[t][lane] + s_tgt[t][lane + 64]
                + s_tgt[t][lane + 128] + s_tgt[t][lane + 192];
        #pragma unroll
        for (int off = 32; off; off >>= 1) v += __shfl_down(v, off, 64);
        if (lane == 0) s_area[t] = v;
    } else if (wid == 8 && lane < 4) {
        int gpix = h * 16 + qx * 4 + lane;
        float s = 0.f;
        #pragma unroll
        for (int t = 0; t < T_; ++t) s += s_tgt[t][gpix];
        s_st[lane] = s;
    }

    // ---------- P2: conv — thread = (channel c, pixel px)
    int c  = tid >> 2;
    int px = tid & 3;
    float acc = 0.f;
    {
        const float* pp = pl + c * PSZ_ + (px + 1);
        const float* wc = wsm + c * 49;
        #pragma unroll
        for (int kh = 0; kh < 7; ++kh)
            #pragma unroll
            for (int kw = 0; kw < 7; ++kw)
                acc += pp[kh * PW_ + kw] * wc[kh * 7 + kw];
    }
    #pragma unroll
    for (int off = 4; off < 64; off <<= 1) acc += __shfl_down(acc, off, 64);
    if (lane < 4) s_red[wid * 4 + lane] = acc;
    __syncthreads();

    // ---------- P3: finish base; cnt/idx per p
    if (tid < 4) {
        float s = 0.f;
        #pragma unroll
        for (int wv = 0; wv < 16; ++wv) s += s_red[wv * 4 + tid];
        s_base[tid] = s;
    } else if (tid >= 64 && tid < 64 + P_) {
        int p = tid - 64;
        int cnt = 0; float best = 3.402823466e38f; int idx = 0;
        #pragma unroll
        for (int t = 0; t < T_; ++t) {
            float on = s_tgt[t][p];
            cnt += (int)on;
            if (on > 0.f && s_area[t] < best) { best = s_area[t]; idx = t; }
        }
        s_cnt[p] = cnt; s_idx[p] = idx;
    }
    __syncthreads();

    // ---------- P4: loss — thread = (p, px)
    float bv = bias[0];
    int p = tid >> 2;
    int gpix = h * 16 + qx * 4 + px;
    int ph = p >> 4, pw = p & 15;
    int dh = ph - h + 3, dw = pw - (qx * 4 + px) + 3;
    float kc = ((unsigned)dh < 7u && (unsigned)dw < 7u) ? s_ktab[dh * 7 + dw] : 0.f;
    float m = 1.f / (1.f + expf(-(s_base[px] + kc + bv)));
    float contrib = (s_cnt[p] > 0) ? fabsf(m - s_tgt[s_idx[p]][gpix])
                                   : s_st[px] * m;

    #pragma unroll
    for (int off = 32; off; off >>= 1) contrib += __shfl_down(contrib, off, 64);
    if (lane == 0) s_red[wid] = contrib;
    __syncthreads();

    // ---------- P5: single-node cross-block combine via ws flags ----------
    float* slotp = ws + (size_t)b * 16;             // 64B per block slot
    unsigned* slotf = (unsigned*)(slotp + 1);

    if (b != 0) {
        if (tid == 0) {
            float bsum = 0.f;
            #pragma unroll
            for (int i = 0; i < 16; ++i) bsum += s_red[i];
            bsum *= (1.0f / 256.0f);
            __hip_atomic_store(slotp, bsum, __ATOMIC_RELAXED, __HIP_MEMORY_SCOPE_AGENT);
            __hip_atomic_store(slotf, MAGIC_, __ATOMIC_RELEASE, __HIP_MEMORY_SCOPE_AGENT);
        }
        return;
    }

    // block 0: consumer
    if (tid == 0) {
        float bsum = 0.f;
        #pragma unroll
        for (int i = 0; i < 16; ++i) bsum += s_red[i];
        s_part[0] = bsum * (1.0f / 256.0f);
    } else if (tid < 128) {
        const float* sp = ws + (size_t)tid * 16;
        const unsigned* sf = (const unsigned*)(sp + 1);
        while (__hip_atomic_load(sf, __ATOMIC_ACQUIRE, __HIP_MEMORY_SCOPE_AGENT) != MAGIC_)
            __builtin_amdgcn_s_sleep(1);
        s_part[tid] = __hip_atomic_load(sp, __ATOMIC_RELAXED, __HIP_MEMORY_SCOPE_AGENT);
    }
    __syncthreads();
    if (tid == 0) {
        float s = 0.f;
        #pragma unroll
        for (int i = 0; i < 128; ++i) s += s_part[i];
        out[0] = s;
    } else if (tid < 128) {
        // reset flags so the next (stream-serialized) replay starts clean
        unsigned* sf = (unsigned*)(ws + (size_t)tid * 16) + 1;
        __hip_atomic_store(sf, 0u, __ATOMIC_RELAXED, __HIP_MEMORY_SCOPE_AGENT);
    }
}

extern "C" void kernel_launch(void* const* d_in, const int* in_sizes, int n_in,
                              void* d_out, int out_size, void* d_ws, size_t ws_size,
                              hipStream_t stream) {
    const float* feat = (const float*)d_in[0];
    const float* wt   = (const float*)d_in[1];
    const float* bias = (const float*)d_in[2];
    const int*   tgt  = (const int*)d_in[3];
    float* out = (float*)d_out;
    float* ws  = (float*)d_ws;

    fused<<<N_ * H_ * 4, 1024, 0, stream>>>(feat, wt, bias, tgt, ws, out);
}

// Round 8
// 13.528 us; speedup vs baseline: 5.3063x; 1.0160x over previous
//
#include <hip/hip_runtime.h>
#include <math.h>

#define N_   2
#define C_   256
#define H_   16
#define W_   16
#define T_   8
#define P_   256
#define MAGIC_ 0x5BD1E995u

// Block = (n, row h, quarter qx): owns 4 pixels (cols qx*4..qx*4+3) of row h.
// 1024 threads = (channel c = tid>>2) x (kh-group g = tid&3); g covers conv
// rows kh in {g, g+4<7}. Plane rows + weights live in REGISTERS straight from
// global (L2-resident) -- no LDS staging for the conv at all.
// Single kernel node: producers publish {partial, flag} in ws (64B slots,
// agent-scope release); block 0 spin-combines, writes out, resets flags.

__global__ __launch_bounds__(1024)
void fused(const float* __restrict__ feat,
           const float* __restrict__ wt,
           const float* __restrict__ bias,
           const int* __restrict__ tgt,
           float* __restrict__ ws,
           float* __restrict__ out) {
    int b = blockIdx.x;                 // n*64 + h*4 + qx
    int tid = threadIdx.x;
    int n = b >> 6, h = (b >> 2) & 15, qx = b & 3;

    __shared__ float s_tgt[T_][P_];     // 8 KB targets (as float)
    __shared__ float s_ktab[49];
    __shared__ float s_area[T_];
    __shared__ float s_st[4];
    __shared__ int   s_cnt[P_];
    __shared__ int   s_idx[P_];
    __shared__ float s_base[4];
    __shared__ float s_red[64];
    __shared__ float s_part[128];

    int c = tid >> 2, g = tid & 3;
    int kh0 = g, kh1 = g + 4;           // kh1 only valid when g < 3

    // ---- issue all global->register loads up front ----
    // plane rows: 12 cols (gc = qx*4-4 .. +8) as 3 float4, zero halo
    const float4* f4 = (const float4*)(feat + (((size_t)(n * C_ + c)) << 8));
    float4 A0 = make_float4(0,0,0,0), A1 = A0, A2 = A0;
    float4 B0 = A0, B1 = A0, B2 = A0;
    int gq = qx - 1;                    // float4-col of k4=0
    {
        int y0 = h - 3 + kh0;
        if ((unsigned)y0 < 16u) {
            if (qx != 0) A0 = f4[(y0 << 2) + gq];
            A1 = f4[(y0 << 2) + gq + 1];
            if (qx != 3) A2 = f4[(y0 << 2) + gq + 2];
        }
        int y1 = h - 3 + kh1;
        if (g < 3 && (unsigned)y1 < 16u) {
            if (qx != 0) B0 = f4[(y1 << 2) + gq];
            B1 = f4[(y1 << 2) + gq + 1];
            if (qx != 3) B2 = f4[(y1 << 2) + gq + 2];
        }
    }
    float w0[7], w1[7];
    {
        const float* wp0 = wt + c * 49 + kh0 * 7;
        #pragma unroll
        for (int j = 0; j < 7; ++j) w0[j] = wp0[j];
        if (g < 3) {
            const float* wp1 = wt + c * 49 + kh1 * 7;
            #pragma unroll
            for (int j = 0; j < 7; ++j) w1[j] = wp1[j];
        } else {
            #pragma unroll
            for (int j = 0; j < 7; ++j) w1[j] = 0.f;
        }
    }

    // ---- stage targets + onehot table (the only LDS staging) ----
    for (int i = tid; i < T_ * P_; i += 1024)
        s_tgt[0][i] = (float)tgt[n * T_ * P_ + i];
    if (tid < 49) s_ktab[tid] = wt[C_ * 49 + tid];
    __syncthreads();

    int wid = tid >> 6, lane = tid & 63;

    // ---- P1: target tables (waves 0..8, concurrent with conv) ----
    if (wid < T_) {
        int t = wid;
        float v = s_tgt[t][lane] + s_tgt[t][lane + 64]
                + s_tgt[t][lane + 128] + s_tgt[t][lane + 192];
        #pragma unroll
        for (int off = 32; off; off >>= 1) v += __shfl_down(v, off, 64);
        if (lane == 0) s_area[t] = v;
    } else if (wid == 8 && lane < 4) {
        int gpix = h * 16 + qx * 4 + lane;
        float s = 0.f;
        #pragma unroll
        for (int t = 0; t < T_; ++t) s += s_tgt[t][gpix];
        s_st[lane] = s;
    }

    // ---- P2: conv, all in registers ----
    float r0[12] = {A0.x,A0.y,A0.z,A0.w, A1.x,A1.y,A1.z,A1.w, A2.x,A2.y,A2.z,A2.w};
    float r1[12] = {B0.x,B0.y,B0.z,B0.w, B1.x,B1.y,B1.z,B1.w, B2.x,B2.y,B2.z,B2.w};
    float acc[4] = {0.f, 0.f, 0.f, 0.f};
    #pragma unroll
    for (int kw = 0; kw < 7; ++kw)
        #pragma unroll
        for (int px = 0; px < 4; ++px)
            acc[px] += r0[px + 1 + kw] * w0[kw] + r1[px + 1 + kw] * w1[kw];

    #pragma unroll
    for (int px = 0; px < 4; ++px) {
        float v = acc[px];
        #pragma unroll
        for (int off = 1; off < 64; off <<= 1) v += __shfl_xor(v, off, 64);
        if (lane == 0) s_red[wid * 4 + px] = v;   // wave sum (4 g x 16 ch)
    }
    __syncthreads();

    // ---- P3: finish base; cnt/idx per p ----
    if (tid < 4) {
        float s = 0.f;
        #pragma unroll
        for (int wv = 0; wv < 16; ++wv) s += s_red[wv * 4 + tid];
        s_base[tid] = s;
    } else if (tid >= 64 && tid < 64 + P_) {
        int p = tid - 64;
        int cnt = 0; float best = 3.402823466e38f; int idx = 0;
        #pragma unroll
        for (int t = 0; t < T_; ++t) {
            float on = s_tgt[t][p];
            cnt += (int)on;
            if (on > 0.f && s_area[t] < best) { best = s_area[t]; idx = t; }
        }
        s_cnt[p] = cnt; s_idx[p] = idx;
    }
    __syncthreads();

    // ---- P4: loss, thread = (p = tid>>2, px = tid&3) ----
    float bv = bias[0];
    int p = tid >> 2, px = tid & 3;
    int gpix = h * 16 + qx * 4 + px;
    int ph = p >> 4, pw = p & 15;
    int dh = ph - h + 3, dw = pw - (qx * 4 + px) + 3;
    float kc = ((unsigned)dh < 7u && (unsigned)dw < 7u) ? s_ktab[dh * 7 + dw] : 0.f;
    float m = 1.f / (1.f + expf(-(s_base[px] + kc + bv)));
    float contrib = (s_cnt[p] > 0) ? fabsf(m - s_tgt[s_idx[p]][gpix])
                                   : s_st[px] * m;

    #pragma unroll
    for (int off = 32; off; off >>= 1) contrib += __shfl_down(contrib, off, 64);
    if (lane == 0) s_red[wid] = contrib;
    __syncthreads();

    // ---- P5: single-node cross-block combine via ws flags ----
    float* slotp = ws + (size_t)b * 16;             // 64B per block slot
    unsigned* slotf = (unsigned*)(slotp + 1);

    if (b != 0) {
        if (tid == 0) {
            float bsum = 0.f;
            #pragma unroll
            for (int i = 0; i < 16; ++i) bsum += s_red[i];
            bsum *= (1.0f / 256.0f);
            __hip_atomic_store(slotp, bsum, __ATOMIC_RELAXED, __HIP_MEMORY_SCOPE_AGENT);
            __hip_atomic_store(slotf, MAGIC_, __ATOMIC_RELEASE, __HIP_MEMORY_SCOPE_AGENT);
        }
        return;
    }

    // block 0: consumer
    if (tid == 0) {
        float bsum = 0.f;
        #pragma unroll
        for (int i = 0; i < 16; ++i) bsum += s_red[i];
        s_part[0] = bsum * (1.0f / 256.0f);
    } else if (tid < 128) {
        const float* sp = ws + (size_t)tid * 16;
        const unsigned* sf = (const unsigned*)(sp + 1);
        while (__hip_atomic_load(sf, __ATOMIC_ACQUIRE, __HIP_MEMORY_SCOPE_AGENT) != MAGIC_)
            __builtin_amdgcn_s_sleep(1);
        s_part[tid] = __hip_atomic_load(sp, __ATOMIC_RELAXED, __HIP_MEMORY_SCOPE_AGENT);
    }
    __syncthreads();
    if (tid < 128) {                    // parallel combine (2 waves)
        float v = s_part[tid];
        #pragma unroll
        for (int off = 1; off < 64; off <<= 1) v += __shfl_xor(v, off, 64);
        if (lane == 0) s_red[32 + wid] = v;
    }
    __syncthreads();
    if (tid == 0) {
        out[0] = s_red[32] + s_red[33];
    } else if (tid < 128) {
        // reset flags so the next (stream-serialized) replay starts clean
        unsigned* sf = (unsigned*)(ws + (size_t)tid * 16) + 1;
        __hip_atomic_store(sf, 0u, __ATOMIC_RELAXED, __HIP_MEMORY_SCOPE_AGENT);
    }
}

extern "C" void kernel_launch(void* const* d_in, const int* in_sizes, int n_in,
                              void* d_out, int out_size, void* d_ws, size_t ws_size,
                              hipStream_t stream) {
    const float* feat = (const float*)d_in[0];
    const float* wt   = (const float*)d_in[1];
    const float* bias = (const float*)d_in[2];
    const int*   tgt  = (const int*)d_in[3];
    float* out = (float*)d_out;
    float* ws  = (float*)d_ws;

    fused<<<N_ * H_ * 4, 1024, 0, stream>>>(feat, wt, bias, tgt, ws, out);
}